// Round 10
// baseline (552.487 us; speedup 1.0000x reference)
//
#include <hip/hip_runtime.h>

// GCN: n=100k nodes, E=1.6M edges, D=64, 3 layers.
// Round 18: feature-sliced gather for L2 residency. R10-R12 proved spmm_gemm is
// L2-MISS-COUNT-bound (invariant to occupancy, VALU work, in-flight loads; FETCH
// pinned 80.6MB): xb 12.8MB >> 4MB per-XCD L2. Fix: xb stored as 4 slices
// [fc][node][16 feats] (3.2MB each, L2-fits); spmm loops fc OUTSIDE rows so
// phase-aligned resident blocks keep one slice hot per L2. Per-edge VALU work
// unchanged; col re-reads are L1-hits. Preprocessing reverted to R8 (best: 345.8).
// Packing (src<<8)|(dst&255) needs n <= 2^17, nbb <= 512.

#define CAPB 8192      // per-bucket slot capacity, dst words & src bytes (mean 4096, 64 sigma)
#define CAP_S2 5120    // LDS staging for sorted col (mean 4096 + 16 sigma)
#define CPAD 16        // cursor stride in ints: one counter per 64B cache line

__device__ __forceinline__ unsigned short f2bf(float f) {   // RNE fp32->bf16
  unsigned u = __float_as_uint(f);
  u += 0x7fff + ((u >> 16) & 1);
  return (unsigned short)(u >> 16);
}
__device__ __forceinline__ float bfs(unsigned short s) { return __uint_as_float((unsigned)s << 16); }

// ---------------- init: padded cursors cur_d/cur_s [b*CPAD] = b*CAPB ----------------
__global__ void init_zero(int* __restrict__ cur_d, int* __restrict__ cur_s) {
  int idx = blockIdx.x * 256 + threadIdx.x;
  if (idx < 512 * CPAD) {
    int v = (idx % CPAD == 0) ? (idx / CPAD) * CAPB : 0;
    cur_d[idx] = v;
    cur_s[idx] = v;
  }
}

// ---------------- one read pass, two LDS-staged coalesced splits (R8) ----------------
__global__ __launch_bounds__(1024) void scatter_both(
    const int* __restrict__ src, const int* __restrict__ dst, int e,
    int* __restrict__ cur_d, int* __restrict__ cur_s,
    unsigned* __restrict__ edges1, unsigned char* __restrict__ srcbuf) {
  __shared__ int stW[4096], stG[4096];
  __shared__ int hist[512], curL[512], gofs[512], psum[512];
  int t = threadIdx.x, b = blockIdx.x;
  int i0 = b * 4096 + 4 * t;
  int sv[4], dv[4];
  if (i0 + 3 < e) {
    int4 s4 = *(const int4*)&src[i0];
    int4 d4 = *(const int4*)&dst[i0];
    sv[0] = s4.x; sv[1] = s4.y; sv[2] = s4.z; sv[3] = s4.w;
    dv[0] = d4.x; dv[1] = d4.y; dv[2] = d4.z; dv[3] = d4.w;
  } else {
    #pragma unroll
    for (int j = 0; j < 4; j++) {
      int idx = i0 + j;
      if (idx < e) { sv[j] = src[idx]; dv[j] = dst[idx]; }
      else { sv[j] = -1; dv[j] = -1; }
    }
  }
  // ======== split 1: by dst bucket ========
  if (t < 512) hist[t] = 0;
  __syncthreads();
  #pragma unroll
  for (int k = 0; k < 4; k++)
    if (dv[k] >= 0) atomicAdd(&hist[dv[k] >> 8], 1);
  __syncthreads();
  if (t < 512) psum[t] = hist[t];
  __syncthreads();
  for (int off = 1; off < 512; off <<= 1) {
    int a = 0;
    if (t < 512 && t >= off) a = psum[t - off];
    __syncthreads();
    if (t < 512) psum[t] += a;
    __syncthreads();
  }
  if (t < 512) {
    int cnt = hist[t];
    int base = psum[t] - cnt;
    curL[t] = base;
    int g = cnt ? atomicAdd(&cur_d[t * CPAD], cnt) : 0;
    gofs[t] = g - base;
  }
  __syncthreads();
  #pragma unroll
  for (int k = 0; k < 4; k++) {
    if (dv[k] >= 0) {
      int bin = dv[k] >> 8;
      int r = atomicAdd(&curL[bin], 1);
      stW[r] = (sv[k] << 8) | (dv[k] & 255);
      stG[r] = gofs[bin] + r;
    }
  }
  __syncthreads();
  int tot = psum[511];
  for (int idx = t; idx < tot; idx += 1024)
    edges1[stG[idx]] = (unsigned)stW[idx];      // coalesced within bucket runs
  __syncthreads();
  // ======== split 2: by src bucket (byte payload) ========
  if (t < 512) hist[t] = 0;
  __syncthreads();
  #pragma unroll
  for (int k = 0; k < 4; k++)
    if (dv[k] >= 0) atomicAdd(&hist[sv[k] >> 8], 1);
  __syncthreads();
  if (t < 512) psum[t] = hist[t];
  __syncthreads();
  for (int off = 1; off < 512; off <<= 1) {
    int a = 0;
    if (t < 512 && t >= off) a = psum[t - off];
    __syncthreads();
    if (t < 512) psum[t] += a;
    __syncthreads();
  }
  if (t < 512) {
    int cnt = hist[t];
    int base = psum[t] - cnt;
    curL[t] = base;
    int g = cnt ? atomicAdd(&cur_s[t * CPAD], cnt) : 0;
    gofs[t] = g - base;
  }
  __syncthreads();
  #pragma unroll
  for (int k = 0; k < 4; k++) {
    if (dv[k] >= 0) {
      int bin = sv[k] >> 8;
      int r = atomicAdd(&curL[bin], 1);
      stW[r] = sv[k] & 255;
      stG[r] = gofs[bin] + r;
    }
  }
  __syncthreads();
  for (int idx = t; idx < tot; idx += 1024)
    srcbuf[stG[idx]] = (unsigned char)stW[idx]; // coalesced byte runs
}

// ---------------- per-bucket fine sort + out-degree (R8): nodes [b*256, +256) ----------
__global__ __launch_bounds__(512) void sort_place(
    const unsigned* __restrict__ edges1, const unsigned char* __restrict__ srcbuf,
    const int* __restrict__ cur_d, const int* __restrict__ cur_s,
    int2* __restrict__ row_be, float* __restrict__ inv_in, float* __restrict__ inv_out,
    int* __restrict__ col, int n) {
  __shared__ int sOut[CAP_S2];
  __shared__ int hist[256], cur[256], psum[256], dhist[256];
  int b = blockIdx.x, t = threadIdx.x;
  int sbase = b * CAPB;
  int ed = cur_d[b * CPAD];           // end of dst slot (words)
  int es = cur_s[b * CPAD];           // end of src slot (bytes)
  int rstart = b << 8;
  int nrows = min(256, n - rstart);
  if (t < 256) { hist[t] = 0; dhist[t] = 0; }
  __syncthreads();
  for (int i = sbase + t; i < ed; i += 512) atomicAdd(&hist[edges1[i] & 255u], 1);
  for (int i = sbase + t; i < es; i += 512) atomicAdd(&dhist[srcbuf[i]], 1);
  __syncthreads();
  int h0 = 0;
  if (t < 256) { h0 = hist[t]; psum[t] = h0; }
  __syncthreads();
  for (int off = 1; off < 256; off <<= 1) {
    int a = 0;
    if (t < 256 && t >= off) a = psum[t - off];
    __syncthreads();
    if (t < 256) psum[t] += a;
    __syncthreads();
  }
  if (t < 256) {
    int ex = psum[t] - h0;
    if (t < nrows) {
      row_be[rstart + t] = make_int2(sbase + ex, sbase + ex + h0);
      inv_in[rstart + t] = rsqrtf(fmaxf((float)h0, 1.0f));
      inv_out[rstart + t] = rsqrtf(fmaxf((float)dhist[t], 1.0f));
    }
    cur[t] = ex;
  }
  __syncthreads();
  for (int i = sbase + t; i < ed; i += 512) {
    unsigned v = edges1[i];
    int pos = atomicAdd(&cur[v & 255u], 1);
    int svv = (int)(v >> 8);
    if (pos < CAP_S2) sOut[pos] = svv;
    else col[sbase + pos] = svv;      // statistically never; correctness fallback
  }
  __syncthreads();
  int m = min(ed - sbase, CAP_S2);
  for (int k = t; k < m; k += 512) col[sbase + k] = sOut[k];
}

// ---------------- wide bf16 cast into SLICED layout [fc][node][16] ------------
__global__ __launch_bounds__(256) void cast_xb(
    const float* __restrict__ node_feat, const float* __restrict__ inv_out,
    unsigned short* __restrict__ xb, int n) {
  int total4 = n * 16;                // 16 float4-chunks (4 feats) per row
  int stride = gridDim.x * 256;
  const float4* nf4 = (const float4*)node_feat;
  for (int u = blockIdx.x * 256 + threadIdx.x; u < total4; u += stride) {
    int r = u >> 4, c = u & 15;       // row, chunk (feats 4c..4c+3)
    float iv = inv_out[r];
    float4 v = nf4[u];
    ushort4 o;
    o.x = f2bf(v.x * iv); o.y = f2bf(v.y * iv);
    o.z = f2bf(v.z * iv); o.w = f2bf(v.w * iv);
    *(ushort4*)&xb[(((size_t)(c >> 2) * n + r) << 4) + ((c & 3) << 2)] = o;
  }
}

// ---------------- fused SpMM + GEMM, feature-sliced gather ----------------
// 512 threads own 64 rows. Gather: fc-loop OUTSIDE rows -> phase-aligned blocks keep
// one 3.2MB slice hot per XCD L2. Per wave: 16 edge-groups x 4 lanes x 4 feats (8B).
// GEMM phase unchanged (W from global, L1-resident). LDS 17.4 KB.
__global__ __launch_bounds__(512) void spmm_gemm(
    const unsigned short* __restrict__ xb,      // sliced [4][n][16]
    const int2* __restrict__ row_be,
    const int* __restrict__ col,
    const float* __restrict__ inv_in, const float* __restrict__ inv_out,
    const float* __restrict__ W, const float* __restrict__ bias,
    float* __restrict__ out_cat, float* __restrict__ out_pool,
    unsigned short* __restrict__ xb_next, int n) {
  __shared__ float sXT[64][68];       // [feat][row]
  int t = threadIdx.x;
  int row0 = blockIdx.x << 6;         // 64 rows per block
  int lane = t & 63;
  int q4 = (lane & 3) << 2;     // feature offset within slice: 0,4,8,12
  int eg = lane >> 2;           // edge group 0..15
  int wv = t >> 6;              // wave 0..7, each owns 8 rows
  for (int fc = 0; fc < 4; fc++) {
    const unsigned short* xs = xb + ((size_t)fc * n << 4);
    for (int k = 0; k < 8; k++) {
      int rl = (wv << 3) + k;
      int row = row0 + rl;
      float val = 0.f;
      if (row < n) {            // wave-uniform
        int2 be = row_be[row];  // L1-hit after fc=0
        float inv = inv_in[row];
        float a0 = 0, a1 = 0, a2 = 0, a3 = 0;
        for (int i = be.x + eg; i < be.y; i += 16) {   // 16 edges in flight
          int c = col[i];       // L1-hit after fc=0 (4KB/block)
          ushort4 u4 = *(const ushort4*)&xs[((size_t)c << 4) + q4];
          a0 += bfs(u4.x); a1 += bfs(u4.y); a2 += bfs(u4.z); a3 += bfs(u4.w);
        }
        // butterfly over edge-group bits (lane bits 2..5)
        a0 += __shfl_xor(a0, 4); a0 += __shfl_xor(a0, 8); a0 += __shfl_xor(a0, 16); a0 += __shfl_xor(a0, 32);
        a1 += __shfl_xor(a1, 4); a1 += __shfl_xor(a1, 8); a1 += __shfl_xor(a1, 16); a1 += __shfl_xor(a1, 32);
        a2 += __shfl_xor(a2, 4); a2 += __shfl_xor(a2, 8); a2 += __shfl_xor(a2, 16); a2 += __shfl_xor(a2, 32);
        a3 += __shfl_xor(a3, 4); a3 += __shfl_xor(a3, 8); a3 += __shfl_xor(a3, 16); a3 += __shfl_xor(a3, 32);
        // lane (q4, eg<4) stores feature fc*16 + q4 + eg (cndmask tree)
        float s0 = (eg & 1) ? a1 : a0;
        float s1 = (eg & 1) ? a3 : a2;
        val = ((eg & 2) ? s1 : s0) * inv;
      }
      if (eg < 4) sXT[(fc << 4) + q4 + eg][rl] = val;
    }
  }
  __syncthreads();
  // ---- GEMM phase: 512 threads, 2x4 micro-tile each -> 64 rows x 64 cols ----
  int tj = t & 15, tr = t >> 4;       // tj: col group 0..15, tr: row group 0..31
  int j4 = tj << 2, r2 = tr << 1;
  const float4 bv = *(const float4*)&bias[j4];
  float4 a0 = bv, a1 = bv;
  #pragma unroll 8
  for (int f = 0; f < 64; f++) {
    float4 w  = *(const float4*)&W[f * 64 + j4];   // L1-resident after first block
    float2 xv = *(const float2*)&sXT[f][r2];
    a0.x = fmaf(xv.x, w.x, a0.x); a0.y = fmaf(xv.x, w.y, a0.y);
    a0.z = fmaf(xv.x, w.z, a0.z); a0.w = fmaf(xv.x, w.w, a0.w);
    a1.x = fmaf(xv.y, w.x, a1.x); a1.y = fmaf(xv.y, w.y, a1.y);
    a1.z = fmaf(xv.y, w.z, a1.z); a1.w = fmaf(xv.y, w.w, a1.w);
  }
  float4 accs[2] = {a0, a1};
  #pragma unroll
  for (int ri = 0; ri < 2; ri++) {
    int row = row0 + r2 + ri;
    if (row < n) {
      float4 h = accs[ri];
      h.x = fmaxf(h.x, 0.f); h.y = fmaxf(h.y, 0.f);
      h.z = fmaxf(h.z, 0.f); h.w = fmaxf(h.w, 0.f);
      *(float4*)&out_cat[(size_t)row * 192 + j4] = h;
      if (xb_next) {
        float sc = inv_out[row];
        ushort4 o;
        o.x = f2bf(h.x * sc); o.y = f2bf(h.y * sc);
        o.z = f2bf(h.z * sc); o.w = f2bf(h.w * sc);
        // sliced layout: slice tj>>2, within-slice chunk tj&3
        *(ushort4*)&xb_next[(((size_t)(tj >> 2) * n + row) << 4) + ((tj & 3) << 2)] = o;
      }
      float part = h.x + h.y + h.z + h.w;
      part += __shfl_xor(part, 1);
      part += __shfl_xor(part, 2);
      part += __shfl_xor(part, 4);
      part += __shfl_xor(part, 8);
      if (tj == 0) out_pool[row] = part;
    }
  }
}

// ---------------- launch ----------------

extern "C" void kernel_launch(void* const* d_in, const int* in_sizes, int n_in,
                              void* d_out, int out_size, void* d_ws, size_t ws_size,
                              hipStream_t stream) {
  const float* node_feat = (const float*)d_in[0];
  const int* src = (const int*)d_in[1];
  const int* dst = (const int*)d_in[2];
  const float* Ws[3] = {(const float*)d_in[4], (const float*)d_in[6], (const float*)d_in[8]};
  const float* bs[3] = {(const float*)d_in[5], (const float*)d_in[7], (const float*)d_in[9]};
  float* out = (float*)d_out;
  int n = in_sizes[0] / 64;
  int e = in_sizes[1];
  int nbb = (n + 255) >> 8;         // buckets of 256 rows (391 for n=100k)
  int nblk = (e + 4095) / 4096;     // edge blocks (391)
  size_t slots = (size_t)nbb * CAPB;

  char* p = (char*)d_ws;
  unsigned short* xba = (unsigned short*)p; p += (size_t)n * 64 * sizeof(unsigned short);
  unsigned short* xbb = (unsigned short*)p; p += (size_t)n * 64 * sizeof(unsigned short);
  float* inv_out = (float*)p;   p += (size_t)n * sizeof(float);
  float* inv_in = (float*)p;    p += (size_t)n * sizeof(float);
  int2* row_be = (int2*)p;      p += (size_t)n * sizeof(int2);
  int* cur_d = (int*)p;         p += 512 * CPAD * sizeof(int);
  int* cur_s = (int*)p;         p += 512 * CPAD * sizeof(int);
  unsigned* edges1 = (unsigned*)p; p += slots * sizeof(unsigned);
  int* col = (int*)p;           p += slots * sizeof(int);
  unsigned char* srcbuf = (unsigned char*)p; p += slots;

  init_zero<<<32, 256, 0, stream>>>(cur_d, cur_s);
  scatter_both<<<nblk, 1024, 0, stream>>>(src, dst, e, cur_d, cur_s, edges1, srcbuf);
  sort_place<<<nbb, 512, 0, stream>>>(edges1, srcbuf, cur_d, cur_s,
                                      row_be, inv_in, inv_out, col, n);
  cast_xb<<<1024, 256, 0, stream>>>(node_feat, inv_out, xba, n);

  float* cat_base = out + (size_t)3 * n;
  int nfb = (n + 63) >> 6;          // fused blocks: 64 rows each (1563 for n=100k)
  // xb double-buffered: fused kernel reads features while writing next layer's.
  spmm_gemm<<<nfb, 512, 0, stream>>>(xba, row_be, col, inv_in, inv_out,
      Ws[0], bs[0], cat_base + 0 * 64, out + (size_t)0 * n, xbb, n);
  spmm_gemm<<<nfb, 512, 0, stream>>>(xbb, row_be, col, inv_in, inv_out,
      Ws[1], bs[1], cat_base + 1 * 64, out + (size_t)1 * n, xba, n);
  spmm_gemm<<<nfb, 512, 0, stream>>>(xba, row_be, col, inv_in, inv_out,
      Ws[2], bs[2], cat_base + 2 * 64, out + (size_t)2 * n, (unsigned short*)nullptr, n);
}

// Round 11
// 348.057 us; speedup vs baseline: 1.5873x; 1.5873x over previous
//
#include <hip/hip_runtime.h>

// GCN: n=100k nodes, E=1.6M edges, D=64, 3 layers.
// Round 19: R8 base (345.8us, best) + nontemporal output streams + cast fusion.
// R18's slicing FAILED (FETCH 80->133MB: half-line utilization + phase drift) ->
// reverted. spmm invariants (R10-R12,R18): bound by L2 miss count on the random
// xb gather. Last cheap lever: spmm writes 38MB/layer of streaming output through
// L2, evicting xb lines (hit rate only ~60% at 12.8MB vs 32MB aggregate). These
// streams are never usefully cached (out_cat not re-read; xb_next read by random
// OTHER XCDs) -> __builtin_nontemporal_store. Also: bf16 cast fused into
// sort_place (cast_xb kernel deleted; R9 proved the pattern, its regression was
// the 1024-bin scan). Packing (src<<8)|(dst&255) needs n <= 2^17, nbb <= 512.

#define CAPB 8192      // per-bucket slot capacity, dst words & src bytes (mean 4096, 64 sigma)
#define CAP_S2 5120    // LDS staging for sorted col (mean 4096 + 16 sigma)
#define CPAD 16        // cursor stride in ints: one counter per 64B cache line

typedef float f4v __attribute__((ext_vector_type(4)));
typedef unsigned short us4v __attribute__((ext_vector_type(4)));

__device__ __forceinline__ unsigned short f2bf(float f) {   // RNE fp32->bf16
  unsigned u = __float_as_uint(f);
  u += 0x7fff + ((u >> 16) & 1);
  return (unsigned short)(u >> 16);
}
__device__ __forceinline__ float bflo(unsigned u) { return __uint_as_float(u << 16); }
__device__ __forceinline__ float bfhi(unsigned u) { return __uint_as_float(u & 0xffff0000u); }

__device__ __forceinline__ void nt_store_f4(float4 v, float* p) {
  f4v x = {v.x, v.y, v.z, v.w};
  __builtin_nontemporal_store(x, (f4v*)p);
}
__device__ __forceinline__ void nt_store_us4(ushort4 v, unsigned short* p) {
  us4v x = {v.x, v.y, v.z, v.w};
  __builtin_nontemporal_store(x, (us4v*)p);
}

// ---------------- init: padded cursors cur_d/cur_s [b*CPAD] = b*CAPB ----------------
__global__ void init_zero(int* __restrict__ cur_d, int* __restrict__ cur_s) {
  int idx = blockIdx.x * 256 + threadIdx.x;
  if (idx < 512 * CPAD) {
    int v = (idx % CPAD == 0) ? (idx / CPAD) * CAPB : 0;
    cur_d[idx] = v;
    cur_s[idx] = v;
  }
}

// ---------------- one read pass, two LDS-staged coalesced splits (R8) ----------------
__global__ __launch_bounds__(1024) void scatter_both(
    const int* __restrict__ src, const int* __restrict__ dst, int e,
    int* __restrict__ cur_d, int* __restrict__ cur_s,
    unsigned* __restrict__ edges1, unsigned char* __restrict__ srcbuf) {
  __shared__ int stW[4096], stG[4096];
  __shared__ int hist[512], curL[512], gofs[512], psum[512];
  int t = threadIdx.x, b = blockIdx.x;
  int i0 = b * 4096 + 4 * t;
  int sv[4], dv[4];
  if (i0 + 3 < e) {
    int4 s4 = *(const int4*)&src[i0];
    int4 d4 = *(const int4*)&dst[i0];
    sv[0] = s4.x; sv[1] = s4.y; sv[2] = s4.z; sv[3] = s4.w;
    dv[0] = d4.x; dv[1] = d4.y; dv[2] = d4.z; dv[3] = d4.w;
  } else {
    #pragma unroll
    for (int j = 0; j < 4; j++) {
      int idx = i0 + j;
      if (idx < e) { sv[j] = src[idx]; dv[j] = dst[idx]; }
      else { sv[j] = -1; dv[j] = -1; }
    }
  }
  // ======== split 1: by dst bucket ========
  if (t < 512) hist[t] = 0;
  __syncthreads();
  #pragma unroll
  for (int k = 0; k < 4; k++)
    if (dv[k] >= 0) atomicAdd(&hist[dv[k] >> 8], 1);
  __syncthreads();
  if (t < 512) psum[t] = hist[t];
  __syncthreads();
  for (int off = 1; off < 512; off <<= 1) {
    int a = 0;
    if (t < 512 && t >= off) a = psum[t - off];
    __syncthreads();
    if (t < 512) psum[t] += a;
    __syncthreads();
  }
  if (t < 512) {
    int cnt = hist[t];
    int base = psum[t] - cnt;
    curL[t] = base;
    int g = cnt ? atomicAdd(&cur_d[t * CPAD], cnt) : 0;
    gofs[t] = g - base;
  }
  __syncthreads();
  #pragma unroll
  for (int k = 0; k < 4; k++) {
    if (dv[k] >= 0) {
      int bin = dv[k] >> 8;
      int r = atomicAdd(&curL[bin], 1);
      stW[r] = (sv[k] << 8) | (dv[k] & 255);
      stG[r] = gofs[bin] + r;
    }
  }
  __syncthreads();
  int tot = psum[511];
  for (int idx = t; idx < tot; idx += 1024)
    edges1[stG[idx]] = (unsigned)stW[idx];      // coalesced within bucket runs
  __syncthreads();
  // ======== split 2: by src bucket (byte payload) ========
  if (t < 512) hist[t] = 0;
  __syncthreads();
  #pragma unroll
  for (int k = 0; k < 4; k++)
    if (dv[k] >= 0) atomicAdd(&hist[sv[k] >> 8], 1);
  __syncthreads();
  if (t < 512) psum[t] = hist[t];
  __syncthreads();
  for (int off = 1; off < 512; off <<= 1) {
    int a = 0;
    if (t < 512 && t >= off) a = psum[t - off];
    __syncthreads();
    if (t < 512) psum[t] += a;
    __syncthreads();
  }
  if (t < 512) {
    int cnt = hist[t];
    int base = psum[t] - cnt;
    curL[t] = base;
    int g = cnt ? atomicAdd(&cur_s[t * CPAD], cnt) : 0;
    gofs[t] = g - base;
  }
  __syncthreads();
  #pragma unroll
  for (int k = 0; k < 4; k++) {
    if (dv[k] >= 0) {
      int bin = sv[k] >> 8;
      int r = atomicAdd(&curL[bin], 1);
      stW[r] = sv[k] & 255;
      stG[r] = gofs[bin] + r;
    }
  }
  __syncthreads();
  for (int idx = t; idx < tot; idx += 1024)
    srcbuf[stG[idx]] = (unsigned char)stW[idx]; // coalesced byte runs
}

// ---------------- per-bucket fine sort + degrees + fused bf16 cast ----------
// block b owns nodes [b*256, +256); dst slot words, src slot bytes; 512 threads.
__global__ __launch_bounds__(512) void sort_place(
    const unsigned* __restrict__ edges1, const unsigned char* __restrict__ srcbuf,
    const int* __restrict__ cur_d, const int* __restrict__ cur_s,
    const float* __restrict__ node_feat,
    int2* __restrict__ row_be, float* __restrict__ inv_in, float* __restrict__ inv_out,
    unsigned short* __restrict__ xb, int* __restrict__ col, int n) {
  __shared__ int sOut[CAP_S2];
  __shared__ int hist[256], cur[256], psum[256], dhist[256];
  __shared__ float sInvO[256];
  int b = blockIdx.x, t = threadIdx.x;
  int sbase = b * CAPB;
  int ed = cur_d[b * CPAD];           // end of dst slot (words)
  int es = cur_s[b * CPAD];           // end of src slot (bytes)
  int rstart = b << 8;
  int nrows = min(256, n - rstart);
  if (t < 256) { hist[t] = 0; dhist[t] = 0; }
  __syncthreads();
  for (int i = sbase + t; i < ed; i += 512) atomicAdd(&hist[edges1[i] & 255u], 1);
  for (int i = sbase + t; i < es; i += 512) atomicAdd(&dhist[srcbuf[i]], 1);
  __syncthreads();
  int h0 = 0;
  if (t < 256) { h0 = hist[t]; psum[t] = h0; }
  __syncthreads();
  for (int off = 1; off < 256; off <<= 1) {
    int a = 0;
    if (t < 256 && t >= off) a = psum[t - off];
    __syncthreads();
    if (t < 256) psum[t] += a;
    __syncthreads();
  }
  if (t < 256) {
    int ex = psum[t] - h0;
    float ivo = rsqrtf(fmaxf((float)dhist[t], 1.0f));
    sInvO[t] = ivo;
    if (t < nrows) {
      row_be[rstart + t] = make_int2(sbase + ex, sbase + ex + h0);
      inv_in[rstart + t] = rsqrtf(fmaxf((float)h0, 1.0f));
      inv_out[rstart + t] = ivo;
    }
    cur[t] = ex;
  }
  __syncthreads();
  for (int i = sbase + t; i < ed; i += 512) {
    unsigned v = edges1[i];
    int pos = atomicAdd(&cur[v & 255u], 1);
    int svv = (int)(v >> 8);
    if (pos < CAP_S2) sOut[pos] = svv;
    else col[sbase + pos] = svv;      // statistically never; correctness fallback
  }
  __syncthreads();
  int m = min(ed - sbase, CAP_S2);
  for (int k = t; k < m; k += 512)
    __builtin_nontemporal_store(sOut[k], &col[sbase + k]);
  // fused pre-scaled bf16 cast of this block's feature rows (sInvO valid since scan)
  int total4 = nrows * 16;            // 16 float4 per row
  const float4* nf4 = (const float4*)(node_feat + (size_t)rstart * 64);
  unsigned short* xrow = xb + (size_t)rstart * 64;
  for (int u = t; u < total4; u += 512) {
    float iv = sInvO[u >> 4];
    float4 v = nf4[u];
    ushort4 o;
    o.x = f2bf(v.x * iv); o.y = f2bf(v.y * iv);
    o.z = f2bf(v.z * iv); o.w = f2bf(v.w * iv);
    nt_store_us4(o, xrow + (size_t)u * 4);
  }
}

// ---------------- fused SpMM + GEMM + bias + ReLU + pool + next-layer bf16 cast ----------------
// 512 threads own 64 rows. Phase 1: 8 waves x 8 rows, wave-per-row gather (16 edges
// in flight, degree-adaptive), shfl-reduce, scaled store into transposed LDS tile sXT.
// Phase 2: 64x64 @ 64x64 GEMM (W from global, L1-resident). Output streams are
// NONTEMPORAL: they are never usefully re-read through this L2 and their 38MB/layer
// was evicting the gather's xb lines.
__global__ __launch_bounds__(512) void spmm_gemm(
    const unsigned short* __restrict__ xb,
    const int2* __restrict__ row_be,
    const int* __restrict__ col,
    const float* __restrict__ inv_in, const float* __restrict__ inv_out,
    const float* __restrict__ W, const float* __restrict__ bias,
    float* __restrict__ out_cat, float* __restrict__ out_pool,
    unsigned short* __restrict__ xb_next, int n) {
  __shared__ float sXT[64][68];       // [feat][row], pad 68 (272B stride, 8B-aligned)
  int t = threadIdx.x;
  int row0 = blockIdx.x << 6;         // 64 rows per block
  int lane = t & 63;
  int g = lane >> 3;            // edge group 0..7
  int l8 = (lane & 7) << 3;     // feature offset (8 feats = 16 B)
  int wv = t >> 6;              // wave 0..7, each owns 8 rows
  for (int k = 0; k < 8; k++) {
    int rl = wv * 8 + k;
    int row = row0 + rl;
    float v = 0.f;
    if (row < n) {              // wave-uniform branch
      int2 be = row_be[row];    // one 8B load: [beg, end)
      int s = be.x, e = be.y;
      float inv = inv_in[row];  // hoisted: overlaps with the edge loop below
      float a0 = 0, a1 = 0, a2 = 0, a3 = 0, a4 = 0, a5 = 0, a6 = 0, a7 = 0;
      int ec = e - 1;
      for (int i = s + g; i < e; i += 16) {   // 16 edges in flight, deg-adaptive
        int i1 = i + 8;
        int c0 = col[i];
        int c1 = col[min(i1, ec)];
        float m1 = (i1 < e) ? 1.f : 0.f;
        uint4 r0 = *(const uint4*)&xb[(size_t)c0 * 64 + l8];
        uint4 r1 = *(const uint4*)&xb[(size_t)c1 * 64 + l8];
        a0 += bflo(r0.x); a1 += bfhi(r0.x); a2 += bflo(r0.y); a3 += bfhi(r0.y);
        a4 += bflo(r0.z); a5 += bfhi(r0.z); a6 += bflo(r0.w); a7 += bfhi(r0.w);
        a0 = fmaf(m1, bflo(r1.x), a0); a1 = fmaf(m1, bfhi(r1.x), a1);
        a2 = fmaf(m1, bflo(r1.y), a2); a3 = fmaf(m1, bfhi(r1.y), a3);
        a4 = fmaf(m1, bflo(r1.z), a4); a5 = fmaf(m1, bfhi(r1.z), a5);
        a6 = fmaf(m1, bflo(r1.w), a6); a7 = fmaf(m1, bfhi(r1.w), a7);
      }
      // butterfly over edge groups (bits 3..5 of lane): all lanes end with full sums
      a0 += __shfl_xor(a0, 8); a0 += __shfl_xor(a0, 16); a0 += __shfl_xor(a0, 32);
      a1 += __shfl_xor(a1, 8); a1 += __shfl_xor(a1, 16); a1 += __shfl_xor(a1, 32);
      a2 += __shfl_xor(a2, 8); a2 += __shfl_xor(a2, 16); a2 += __shfl_xor(a2, 32);
      a3 += __shfl_xor(a3, 8); a3 += __shfl_xor(a3, 16); a3 += __shfl_xor(a3, 32);
      a4 += __shfl_xor(a4, 8); a4 += __shfl_xor(a4, 16); a4 += __shfl_xor(a4, 32);
      a5 += __shfl_xor(a5, 8); a5 += __shfl_xor(a5, 16); a5 += __shfl_xor(a5, 32);
      a6 += __shfl_xor(a6, 8); a6 += __shfl_xor(a6, 16); a6 += __shfl_xor(a6, 32);
      a7 += __shfl_xor(a7, 8); a7 += __shfl_xor(a7, 16); a7 += __shfl_xor(a7, 32);
      // lane (g,l8) contributes feature f = l8 + g (cndmask tree, no scratch array)
      float s0 = (g & 1) ? a1 : a0;
      float s1 = (g & 1) ? a3 : a2;
      float s2 = (g & 1) ? a5 : a4;
      float s3 = (g & 1) ? a7 : a6;
      float u0 = (g & 2) ? s1 : s0;
      float u1 = (g & 2) ? s3 : s2;
      v = ((g & 4) ? u1 : u0) * inv;
    }
    sXT[l8 + g][rl] = v;        // 64 lanes -> 64 feats of column rl (8-way, single store)
  }
  __syncthreads();
  // ---- GEMM phase: 512 threads, 2x4 micro-tile each -> 64 rows x 64 cols ----
  int tj = t & 15, tr = t >> 4;       // tj: col group 0..15, tr: row group 0..31
  int j4 = tj << 2, r2 = tr << 1;
  const float4 bv = *(const float4*)&bias[j4];
  float4 a0 = bv, a1 = bv;
  #pragma unroll 8
  for (int f = 0; f < 64; f++) {
    float4 w  = *(const float4*)&W[f * 64 + j4];   // L1-resident after first block
    float2 xv = *(const float2*)&sXT[f][r2];
    a0.x = fmaf(xv.x, w.x, a0.x); a0.y = fmaf(xv.x, w.y, a0.y);
    a0.z = fmaf(xv.x, w.z, a0.z); a0.w = fmaf(xv.x, w.w, a0.w);
    a1.x = fmaf(xv.y, w.x, a1.x); a1.y = fmaf(xv.y, w.y, a1.y);
    a1.z = fmaf(xv.y, w.z, a1.z); a1.w = fmaf(xv.y, w.w, a1.w);
  }
  float4 accs[2] = {a0, a1};
  #pragma unroll
  for (int ri = 0; ri < 2; ri++) {
    int row = row0 + r2 + ri;
    if (row < n) {
      float4 h = accs[ri];
      h.x = fmaxf(h.x, 0.f); h.y = fmaxf(h.y, 0.f);
      h.z = fmaxf(h.z, 0.f); h.w = fmaxf(h.w, 0.f);
      nt_store_f4(h, &out_cat[(size_t)row * 192 + j4]);
      if (xb_next) {
        float sc = inv_out[row];
        ushort4 o;
        o.x = f2bf(h.x * sc); o.y = f2bf(h.y * sc);
        o.z = f2bf(h.z * sc); o.w = f2bf(h.w * sc);
        nt_store_us4(o, &xb_next[(size_t)row * 64 + j4]);
      }
      float part = h.x + h.y + h.z + h.w;
      part += __shfl_xor(part, 1);
      part += __shfl_xor(part, 2);
      part += __shfl_xor(part, 4);
      part += __shfl_xor(part, 8);
      if (tj == 0) __builtin_nontemporal_store(part, &out_pool[row]);
    }
  }
}

// ---------------- launch ----------------

extern "C" void kernel_launch(void* const* d_in, const int* in_sizes, int n_in,
                              void* d_out, int out_size, void* d_ws, size_t ws_size,
                              hipStream_t stream) {
  const float* node_feat = (const float*)d_in[0];
  const int* src = (const int*)d_in[1];
  const int* dst = (const int*)d_in[2];
  const float* Ws[3] = {(const float*)d_in[4], (const float*)d_in[6], (const float*)d_in[8]};
  const float* bs[3] = {(const float*)d_in[5], (const float*)d_in[7], (const float*)d_in[9]};
  float* out = (float*)d_out;
  int n = in_sizes[0] / 64;
  int e = in_sizes[1];
  int nbb = (n + 255) >> 8;         // buckets of 256 rows (391 for n=100k)
  int nblk = (e + 4095) / 4096;     // edge blocks (391)
  size_t slots = (size_t)nbb * CAPB;

  char* p = (char*)d_ws;
  unsigned short* xba = (unsigned short*)p; p += (size_t)n * 64 * sizeof(unsigned short);
  unsigned short* xbb = (unsigned short*)p; p += (size_t)n * 64 * sizeof(unsigned short);
  float* inv_out = (float*)p;   p += (size_t)n * sizeof(float);
  float* inv_in = (float*)p;    p += (size_t)n * sizeof(float);
  int2* row_be = (int2*)p;      p += (size_t)n * sizeof(int2);
  int* cur_d = (int*)p;         p += 512 * CPAD * sizeof(int);
  int* cur_s = (int*)p;         p += 512 * CPAD * sizeof(int);
  unsigned* edges1 = (unsigned*)p; p += slots * sizeof(unsigned);
  int* col = (int*)p;           p += slots * sizeof(int);
  unsigned char* srcbuf = (unsigned char*)p; p += slots;

  init_zero<<<32, 256, 0, stream>>>(cur_d, cur_s);
  scatter_both<<<nblk, 1024, 0, stream>>>(src, dst, e, cur_d, cur_s, edges1, srcbuf);
  sort_place<<<nbb, 512, 0, stream>>>(edges1, srcbuf, cur_d, cur_s, node_feat,
                                      row_be, inv_in, inv_out, xba, col, n);

  float* cat_base = out + (size_t)3 * n;
  int nfb = (n + 63) >> 6;          // fused blocks: 64 rows each (1563 for n=100k)
  // xb double-buffered: fused kernel reads features while writing next layer's.
  spmm_gemm<<<nfb, 512, 0, stream>>>(xba, row_be, col, inv_in, inv_out,
      Ws[0], bs[0], cat_base + 0 * 64, out + (size_t)0 * n, xbb, n);
  spmm_gemm<<<nfb, 512, 0, stream>>>(xbb, row_be, col, inv_in, inv_out,
      Ws[1], bs[1], cat_base + 1 * 64, out + (size_t)1 * n, xba, n);
  spmm_gemm<<<nfb, 512, 0, stream>>>(xba, row_be, col, inv_in, inv_out,
      Ws[2], bs[2], cat_base + 2 * 64, out + (size_t)2 * n, (unsigned short*)nullptr, n);
}

// Round 12
// 340.979 us; speedup vs baseline: 1.6203x; 1.0208x over previous
//
#include <hip/hip_runtime.h>

// GCN: n=100k nodes, E=1.6M edges, D=64, 3 layers.
// Round 20: sort_place v2. spmm_gemm declared at floor (5 null probes: occupancy,
// VALU work, in-flight loads, layout, NT writes; 75us/layer, FETCH ~78MB pinned).
// Remaining slack is preprocessing (~122us). sort_place defects: 391 blocks =
// 1.53/CU, 512 threads, edges1 read TWICE from global. Fix: 1024 threads (16
// waves), full bucket staged in LDS sEdge[8192] (one global read; hist+placement
// at LDS speed), sOut full-size (fallback deleted). LDS 69KB (160KB/CU on MI355X).
// R11's NT-store mistake reverted: NT kept ONLY on out_cat/out_pool (never
// re-read); col/xb/xb_next are re-read -> plain stores.
// Packing (src<<8)|(dst&255) needs n <= 2^17, nbb <= 512.

#define CAPB 8192      // per-bucket slot capacity, dst words & src bytes (mean 4096, 64 sigma)
#define CPAD 16        // cursor stride in ints: one counter per 64B cache line

typedef float f4v __attribute__((ext_vector_type(4)));

__device__ __forceinline__ unsigned short f2bf(float f) {   // RNE fp32->bf16
  unsigned u = __float_as_uint(f);
  u += 0x7fff + ((u >> 16) & 1);
  return (unsigned short)(u >> 16);
}
__device__ __forceinline__ float bflo(unsigned u) { return __uint_as_float(u << 16); }
__device__ __forceinline__ float bfhi(unsigned u) { return __uint_as_float(u & 0xffff0000u); }

__device__ __forceinline__ void nt_store_f4(float4 v, float* p) {
  f4v x = {v.x, v.y, v.z, v.w};
  __builtin_nontemporal_store(x, (f4v*)p);
}

// ---------------- init: padded cursors cur_d/cur_s [b*CPAD] = b*CAPB ----------------
__global__ void init_zero(int* __restrict__ cur_d, int* __restrict__ cur_s) {
  int idx = blockIdx.x * 256 + threadIdx.x;
  if (idx < 512 * CPAD) {
    int v = (idx % CPAD == 0) ? (idx / CPAD) * CAPB : 0;
    cur_d[idx] = v;
    cur_s[idx] = v;
  }
}

// ---------------- one read pass, two LDS-staged coalesced splits (R8) ----------------
__global__ __launch_bounds__(1024) void scatter_both(
    const int* __restrict__ src, const int* __restrict__ dst, int e,
    int* __restrict__ cur_d, int* __restrict__ cur_s,
    unsigned* __restrict__ edges1, unsigned char* __restrict__ srcbuf) {
  __shared__ int stW[4096], stG[4096];
  __shared__ int hist[512], curL[512], gofs[512], psum[512];
  int t = threadIdx.x, b = blockIdx.x;
  int i0 = b * 4096 + 4 * t;
  int sv[4], dv[4];
  if (i0 + 3 < e) {
    int4 s4 = *(const int4*)&src[i0];
    int4 d4 = *(const int4*)&dst[i0];
    sv[0] = s4.x; sv[1] = s4.y; sv[2] = s4.z; sv[3] = s4.w;
    dv[0] = d4.x; dv[1] = d4.y; dv[2] = d4.z; dv[3] = d4.w;
  } else {
    #pragma unroll
    for (int j = 0; j < 4; j++) {
      int idx = i0 + j;
      if (idx < e) { sv[j] = src[idx]; dv[j] = dst[idx]; }
      else { sv[j] = -1; dv[j] = -1; }
    }
  }
  // ======== split 1: by dst bucket ========
  if (t < 512) hist[t] = 0;
  __syncthreads();
  #pragma unroll
  for (int k = 0; k < 4; k++)
    if (dv[k] >= 0) atomicAdd(&hist[dv[k] >> 8], 1);
  __syncthreads();
  if (t < 512) psum[t] = hist[t];
  __syncthreads();
  for (int off = 1; off < 512; off <<= 1) {
    int a = 0;
    if (t < 512 && t >= off) a = psum[t - off];
    __syncthreads();
    if (t < 512) psum[t] += a;
    __syncthreads();
  }
  if (t < 512) {
    int cnt = hist[t];
    int base = psum[t] - cnt;
    curL[t] = base;
    int g = cnt ? atomicAdd(&cur_d[t * CPAD], cnt) : 0;
    gofs[t] = g - base;
  }
  __syncthreads();
  #pragma unroll
  for (int k = 0; k < 4; k++) {
    if (dv[k] >= 0) {
      int bin = dv[k] >> 8;
      int r = atomicAdd(&curL[bin], 1);
      stW[r] = (sv[k] << 8) | (dv[k] & 255);
      stG[r] = gofs[bin] + r;
    }
  }
  __syncthreads();
  int tot = psum[511];
  for (int idx = t; idx < tot; idx += 1024)
    edges1[stG[idx]] = (unsigned)stW[idx];      // coalesced within bucket runs
  __syncthreads();
  // ======== split 2: by src bucket (byte payload) ========
  if (t < 512) hist[t] = 0;
  __syncthreads();
  #pragma unroll
  for (int k = 0; k < 4; k++)
    if (dv[k] >= 0) atomicAdd(&hist[sv[k] >> 8], 1);
  __syncthreads();
  if (t < 512) psum[t] = hist[t];
  __syncthreads();
  for (int off = 1; off < 512; off <<= 1) {
    int a = 0;
    if (t < 512 && t >= off) a = psum[t - off];
    __syncthreads();
    if (t < 512) psum[t] += a;
    __syncthreads();
  }
  if (t < 512) {
    int cnt = hist[t];
    int base = psum[t] - cnt;
    curL[t] = base;
    int g = cnt ? atomicAdd(&cur_s[t * CPAD], cnt) : 0;
    gofs[t] = g - base;
  }
  __syncthreads();
  #pragma unroll
  for (int k = 0; k < 4; k++) {
    if (dv[k] >= 0) {
      int bin = sv[k] >> 8;
      int r = atomicAdd(&curL[bin], 1);
      stW[r] = sv[k] & 255;
      stG[r] = gofs[bin] + r;
    }
  }
  __syncthreads();
  for (int idx = t; idx < tot; idx += 1024)
    srcbuf[stG[idx]] = (unsigned char)stW[idx]; // coalesced byte runs
}

// ---------------- per-bucket fine sort + degrees + fused bf16 cast (v2) ----------
// block b owns nodes [b*256, +256); 1024 threads, full bucket staged in LDS.
__global__ __launch_bounds__(1024) void sort_place(
    const unsigned* __restrict__ edges1, const unsigned char* __restrict__ srcbuf,
    const int* __restrict__ cur_d, const int* __restrict__ cur_s,
    const float* __restrict__ node_feat,
    int2* __restrict__ row_be, float* __restrict__ inv_in, float* __restrict__ inv_out,
    unsigned short* __restrict__ xb, int* __restrict__ col, int n) {
  __shared__ int sEdge[CAPB];         // 32 KB staged bucket edges
  __shared__ int sOut[CAPB];          // 32 KB sorted src ids (full size, no fallback)
  __shared__ int hist[256], cur[256], psum[256], dhist[256];
  __shared__ float sInvO[256];
  int b = blockIdx.x, t = threadIdx.x;
  int sbase = b * CAPB;
  int m = min(cur_d[b * CPAD] - sbase, CAPB);   // bucket edge count
  int ms = min(cur_s[b * CPAD] - sbase, CAPB);  // src-side byte count
  int rstart = b << 8;
  int nrows = min(256, n - rstart);
  if (t < 256) { hist[t] = 0; dhist[t] = 0; }
  __syncthreads();
  // one global pass: stage edges; out-degree hist straight from byte buffer
  for (int k = t; k < m; k += 1024) sEdge[k] = (int)edges1[sbase + k];
  for (int k = t; k < ms; k += 1024) atomicAdd(&dhist[srcbuf[sbase + k]], 1);
  __syncthreads();
  // in-degree hist from LDS
  for (int k = t; k < m; k += 1024) atomicAdd(&hist[sEdge[k] & 255], 1);
  __syncthreads();
  int h0 = 0;
  if (t < 256) { h0 = hist[t]; psum[t] = h0; }
  __syncthreads();
  for (int off = 1; off < 256; off <<= 1) {
    int a = 0;
    if (t < 256 && t >= off) a = psum[t - off];
    __syncthreads();
    if (t < 256) psum[t] += a;
    __syncthreads();
  }
  if (t < 256) {
    int ex = psum[t] - h0;
    float ivo = rsqrtf(fmaxf((float)dhist[t], 1.0f));
    sInvO[t] = ivo;
    if (t < nrows) {
      row_be[rstart + t] = make_int2(sbase + ex, sbase + ex + h0);
      inv_in[rstart + t] = rsqrtf(fmaxf((float)h0, 1.0f));
      inv_out[rstart + t] = ivo;
    }
    cur[t] = ex;
  }
  __syncthreads();
  // place LDS -> LDS (pos < m <= CAPB always)
  for (int k = t; k < m; k += 1024) {
    int v = sEdge[k];
    int pos = atomicAdd(&cur[v & 255], 1);
    sOut[pos] = v >> 8;
  }
  __syncthreads();
  for (int k = t; k < m; k += 1024) col[sbase + k] = sOut[k];
  // fused pre-scaled bf16 cast of this block's feature rows
  int total4 = nrows * 16;            // 16 float4 per row
  const float4* nf4 = (const float4*)(node_feat + (size_t)rstart * 64);
  unsigned short* xrow = xb + (size_t)rstart * 64;
  for (int u = t; u < total4; u += 1024) {
    float iv = sInvO[u >> 4];
    float4 v = nf4[u];
    ushort4 o;
    o.x = f2bf(v.x * iv); o.y = f2bf(v.y * iv);
    o.z = f2bf(v.z * iv); o.w = f2bf(v.w * iv);
    *(ushort4*)&xrow[(size_t)u * 4] = o;
  }
}

// ---------------- fused SpMM + GEMM + bias + ReLU + pool + next-layer bf16 cast ----------------
// 512 threads own 64 rows. Phase 1: 8 waves x 8 rows, wave-per-row gather (16 edges
// in flight, degree-adaptive), shfl-reduce, scaled store into transposed LDS tile sXT.
// Phase 2: 64x64 @ 64x64 GEMM (W from global, L1-resident). NT stores ONLY on
// out_cat/out_pool (never re-read); xb_next is re-read next layer -> plain store.
__global__ __launch_bounds__(512) void spmm_gemm(
    const unsigned short* __restrict__ xb,
    const int2* __restrict__ row_be,
    const int* __restrict__ col,
    const float* __restrict__ inv_in, const float* __restrict__ inv_out,
    const float* __restrict__ W, const float* __restrict__ bias,
    float* __restrict__ out_cat, float* __restrict__ out_pool,
    unsigned short* __restrict__ xb_next, int n) {
  __shared__ float sXT[64][68];       // [feat][row], pad 68 (272B stride, 8B-aligned)
  int t = threadIdx.x;
  int row0 = blockIdx.x << 6;         // 64 rows per block
  int lane = t & 63;
  int g = lane >> 3;            // edge group 0..7
  int l8 = (lane & 7) << 3;     // feature offset (8 feats = 16 B)
  int wv = t >> 6;              // wave 0..7, each owns 8 rows
  for (int k = 0; k < 8; k++) {
    int rl = wv * 8 + k;
    int row = row0 + rl;
    float v = 0.f;
    if (row < n) {              // wave-uniform branch
      int2 be = row_be[row];    // one 8B load: [beg, end)
      int s = be.x, e = be.y;
      float inv = inv_in[row];  // hoisted: overlaps with the edge loop below
      float a0 = 0, a1 = 0, a2 = 0, a3 = 0, a4 = 0, a5 = 0, a6 = 0, a7 = 0;
      int ec = e - 1;
      for (int i = s + g; i < e; i += 16) {   // 16 edges in flight, deg-adaptive
        int i1 = i + 8;
        int c0 = col[i];
        int c1 = col[min(i1, ec)];
        float m1 = (i1 < e) ? 1.f : 0.f;
        uint4 r0 = *(const uint4*)&xb[(size_t)c0 * 64 + l8];
        uint4 r1 = *(const uint4*)&xb[(size_t)c1 * 64 + l8];
        a0 += bflo(r0.x); a1 += bfhi(r0.x); a2 += bflo(r0.y); a3 += bfhi(r0.y);
        a4 += bflo(r0.z); a5 += bfhi(r0.z); a6 += bflo(r0.w); a7 += bfhi(r0.w);
        a0 = fmaf(m1, bflo(r1.x), a0); a1 = fmaf(m1, bfhi(r1.x), a1);
        a2 = fmaf(m1, bflo(r1.y), a2); a3 = fmaf(m1, bfhi(r1.y), a3);
        a4 = fmaf(m1, bflo(r1.z), a4); a5 = fmaf(m1, bfhi(r1.z), a5);
        a6 = fmaf(m1, bflo(r1.w), a6); a7 = fmaf(m1, bfhi(r1.w), a7);
      }
      // butterfly over edge groups (bits 3..5 of lane): all lanes end with full sums
      a0 += __shfl_xor(a0, 8); a0 += __shfl_xor(a0, 16); a0 += __shfl_xor(a0, 32);
      a1 += __shfl_xor(a1, 8); a1 += __shfl_xor(a1, 16); a1 += __shfl_xor(a1, 32);
      a2 += __shfl_xor(a2, 8); a2 += __shfl_xor(a2, 16); a2 += __shfl_xor(a2, 32);
      a3 += __shfl_xor(a3, 8); a3 += __shfl_xor(a3, 16); a3 += __shfl_xor(a3, 32);
      a4 += __shfl_xor(a4, 8); a4 += __shfl_xor(a4, 16); a4 += __shfl_xor(a4, 32);
      a5 += __shfl_xor(a5, 8); a5 += __shfl_xor(a5, 16); a5 += __shfl_xor(a5, 32);
      a6 += __shfl_xor(a6, 8); a6 += __shfl_xor(a6, 16); a6 += __shfl_xor(a6, 32);
      a7 += __shfl_xor(a7, 8); a7 += __shfl_xor(a7, 16); a7 += __shfl_xor(a7, 32);
      // lane (g,l8) contributes feature f = l8 + g (cndmask tree, no scratch array)
      float s0 = (g & 1) ? a1 : a0;
      float s1 = (g & 1) ? a3 : a2;
      float s2 = (g & 1) ? a5 : a4;
      float s3 = (g & 1) ? a7 : a6;
      float u0 = (g & 2) ? s1 : s0;
      float u1 = (g & 2) ? s3 : s2;
      v = ((g & 4) ? u1 : u0) * inv;
    }
    sXT[l8 + g][rl] = v;        // 64 lanes -> 64 feats of column rl (8-way, single store)
  }
  __syncthreads();
  // ---- GEMM phase: 512 threads, 2x4 micro-tile each -> 64 rows x 64 cols ----
  int tj = t & 15, tr = t >> 4;       // tj: col group 0..15, tr: row group 0..31
  int j4 = tj << 2, r2 = tr << 1;
  const float4 bv = *(const float4*)&bias[j4];
  float4 a0 = bv, a1 = bv;
  #pragma unroll 8
  for (int f = 0; f < 64; f++) {
    float4 w  = *(const float4*)&W[f * 64 + j4];   // L1-resident after first block
    float2 xv = *(const float2*)&sXT[f][r2];
    a0.x = fmaf(xv.x, w.x, a0.x); a0.y = fmaf(xv.x, w.y, a0.y);
    a0.z = fmaf(xv.x, w.z, a0.z); a0.w = fmaf(xv.x, w.w, a0.w);
    a1.x = fmaf(xv.y, w.x, a1.x); a1.y = fmaf(xv.y, w.y, a1.y);
    a1.z = fmaf(xv.y, w.z, a1.z); a1.w = fmaf(xv.y, w.w, a1.w);
  }
  float4 accs[2] = {a0, a1};
  #pragma unroll
  for (int ri = 0; ri < 2; ri++) {
    int row = row0 + r2 + ri;
    if (row < n) {
      float4 h = accs[ri];
      h.x = fmaxf(h.x, 0.f); h.y = fmaxf(h.y, 0.f);
      h.z = fmaxf(h.z, 0.f); h.w = fmaxf(h.w, 0.f);
      nt_store_f4(h, &out_cat[(size_t)row * 192 + j4]);
      if (xb_next) {
        float sc = inv_out[row];
        ushort4 o;
        o.x = f2bf(h.x * sc); o.y = f2bf(h.y * sc);
        o.z = f2bf(h.z * sc); o.w = f2bf(h.w * sc);
        *(ushort4*)&xb_next[(size_t)row * 64 + j4] = o;
      }
      float part = h.x + h.y + h.z + h.w;
      part += __shfl_xor(part, 1);
      part += __shfl_xor(part, 2);
      part += __shfl_xor(part, 4);
      part += __shfl_xor(part, 8);
      if (tj == 0) __builtin_nontemporal_store(part, &out_pool[row]);
    }
  }
}

// ---------------- launch ----------------

extern "C" void kernel_launch(void* const* d_in, const int* in_sizes, int n_in,
                              void* d_out, int out_size, void* d_ws, size_t ws_size,
                              hipStream_t stream) {
  const float* node_feat = (const float*)d_in[0];
  const int* src = (const int*)d_in[1];
  const int* dst = (const int*)d_in[2];
  const float* Ws[3] = {(const float*)d_in[4], (const float*)d_in[6], (const float*)d_in[8]};
  const float* bs[3] = {(const float*)d_in[5], (const float*)d_in[7], (const float*)d_in[9]};
  float* out = (float*)d_out;
  int n = in_sizes[0] / 64;
  int e = in_sizes[1];
  int nbb = (n + 255) >> 8;         // buckets of 256 rows (391 for n=100k)
  int nblk = (e + 4095) / 4096;     // edge blocks (391)
  size_t slots = (size_t)nbb * CAPB;

  char* p = (char*)d_ws;
  unsigned short* xba = (unsigned short*)p; p += (size_t)n * 64 * sizeof(unsigned short);
  unsigned short* xbb = (unsigned short*)p; p += (size_t)n * 64 * sizeof(unsigned short);
  float* inv_out = (float*)p;   p += (size_t)n * sizeof(float);
  float* inv_in = (float*)p;    p += (size_t)n * sizeof(float);
  int2* row_be = (int2*)p;      p += (size_t)n * sizeof(int2);
  int* cur_d = (int*)p;         p += 512 * CPAD * sizeof(int);
  int* cur_s = (int*)p;         p += 512 * CPAD * sizeof(int);
  unsigned* edges1 = (unsigned*)p; p += slots * sizeof(unsigned);
  int* col = (int*)p;           p += slots * sizeof(int);
  unsigned char* srcbuf = (unsigned char*)p; p += slots;

  init_zero<<<32, 256, 0, stream>>>(cur_d, cur_s);
  scatter_both<<<nblk, 1024, 0, stream>>>(src, dst, e, cur_d, cur_s, edges1, srcbuf);
  sort_place<<<nbb, 1024, 0, stream>>>(edges1, srcbuf, cur_d, cur_s, node_feat,
                                       row_be, inv_in, inv_out, xba, col, n);

  float* cat_base = out + (size_t)3 * n;
  int nfb = (n + 63) >> 6;          // fused blocks: 64 rows each (1563 for n=100k)
  // xb double-buffered: fused kernel reads features while writing next layer's.
  spmm_gemm<<<nfb, 512, 0, stream>>>(xba, row_be, col, inv_in, inv_out,
      Ws[0], bs[0], cat_base + 0 * 64, out + (size_t)0 * n, xbb, n);
  spmm_gemm<<<nfb, 512, 0, stream>>>(xbb, row_be, col, inv_in, inv_out,
      Ws[1], bs[1], cat_base + 1 * 64, out + (size_t)1 * n, xba, n);
  spmm_gemm<<<nfb, 512, 0, stream>>>(xba, row_be, col, inv_in, inv_out,
      Ws[2], bs[2], cat_base + 2 * 64, out + (size_t)2 * n, (unsigned short*)nullptr, n);
}

// Round 13
// 333.640 us; speedup vs baseline: 1.6559x; 1.0220x over previous
//
#include <hip/hip_runtime.h>

// GCN: n=100k nodes, E=1.6M edges, D=64, 3 layers.
// Round 21: scatter full-line runs + sXT pad fix. R20 = 341.0 best. spmm declared
// structural floor (74us/layer: ~617k L2 misses = MSHR-queue-bound on random
// gather; 6 null/negative probes). Remaining defects: (1) scatter bucket runs
// were ~8 words = 32B sub-line -> ~3x write amp; now 8192 edges/block (196
// blocks), runs ~16 words = 64B full line; stG(int) replaced by stB(ushort)
// bin-map to fit 56KB LDS. (2) sXT stride 68 words = 8-way bank conflict on the
// scatter-store (1.4M conflict cycles); pad 66 -> 4-way, still 8B-aligned.
// Packing (src<<8)|(dst&255) needs n <= 2^17, nbb <= 512.

#define CAPB 8192      // per-bucket slot capacity, dst words & src bytes (mean 4096, 64 sigma)
#define EPB  8192      // edges per scatter block
#define CPAD 16        // cursor stride in ints: one counter per 64B cache line

typedef float f4v __attribute__((ext_vector_type(4)));

__device__ __forceinline__ unsigned short f2bf(float f) {   // RNE fp32->bf16
  unsigned u = __float_as_uint(f);
  u += 0x7fff + ((u >> 16) & 1);
  return (unsigned short)(u >> 16);
}
__device__ __forceinline__ float bflo(unsigned u) { return __uint_as_float(u << 16); }
__device__ __forceinline__ float bfhi(unsigned u) { return __uint_as_float(u & 0xffff0000u); }

__device__ __forceinline__ void nt_store_f4(float4 v, float* p) {
  f4v x = {v.x, v.y, v.z, v.w};
  __builtin_nontemporal_store(x, (f4v*)p);
}

// ---------------- init: padded cursors cur_d/cur_s [b*CPAD] = b*CAPB ----------------
__global__ void init_zero(int* __restrict__ cur_d, int* __restrict__ cur_s) {
  int idx = blockIdx.x * 256 + threadIdx.x;
  if (idx < 512 * CPAD) {
    int v = (idx % CPAD == 0) ? (idx / CPAD) * CAPB : 0;
    cur_d[idx] = v;
    cur_s[idx] = v;
  }
}

// ---------------- one read pass, two LDS-staged coalesced splits ----------------
// 1024 threads x 8 edges = 8192 edges/block (196 blocks): bucket runs ~16 words
// = 64B full lines. Placement records bin in stB (ushort); write loop uses
// gofs[stB[idx]] + idx. Split 2 reuses stW/stB for the src-bucket byte payload.
__global__ __launch_bounds__(1024) void scatter_both(
    const int* __restrict__ src, const int* __restrict__ dst, int e,
    int* __restrict__ cur_d, int* __restrict__ cur_s,
    unsigned* __restrict__ edges1, unsigned char* __restrict__ srcbuf) {
  __shared__ int stW[EPB];            // 32 KB payloads in bucket order
  __shared__ unsigned short stB[EPB]; // 16 KB bin of each placed element
  __shared__ int hist[512], curL[512], gofs[512], psum[512];
  int t = threadIdx.x, b = blockIdx.x;
  int i0 = b * EPB + 8 * t;
  int sv[8], dv[8];
  #pragma unroll
  for (int k = 0; k < 8; k += 4) {
    int i = i0 + k;
    if (i + 3 < e) {
      int4 s4 = *(const int4*)&src[i];
      int4 d4 = *(const int4*)&dst[i];
      sv[k] = s4.x; sv[k+1] = s4.y; sv[k+2] = s4.z; sv[k+3] = s4.w;
      dv[k] = d4.x; dv[k+1] = d4.y; dv[k+2] = d4.z; dv[k+3] = d4.w;
    } else {
      #pragma unroll
      for (int j = 0; j < 4; j++) {
        int idx = i + j;
        if (idx < e) { sv[k+j] = src[idx]; dv[k+j] = dst[idx]; }
        else { sv[k+j] = -1; dv[k+j] = -1; }
      }
    }
  }
  // ======== split 1: by dst bucket ========
  if (t < 512) hist[t] = 0;
  __syncthreads();
  #pragma unroll
  for (int k = 0; k < 8; k++)
    if (dv[k] >= 0) atomicAdd(&hist[dv[k] >> 8], 1);
  __syncthreads();
  if (t < 512) psum[t] = hist[t];
  __syncthreads();
  for (int off = 1; off < 512; off <<= 1) {
    int a = 0;
    if (t < 512 && t >= off) a = psum[t - off];
    __syncthreads();
    if (t < 512) psum[t] += a;
    __syncthreads();
  }
  if (t < 512) {
    int cnt = hist[t];
    int base = psum[t] - cnt;
    curL[t] = base;
    int g = cnt ? atomicAdd(&cur_d[t * CPAD], cnt) : 0;
    gofs[t] = g - base;
  }
  __syncthreads();
  #pragma unroll
  for (int k = 0; k < 8; k++) {
    if (dv[k] >= 0) {
      int bin = dv[k] >> 8;
      int r = atomicAdd(&curL[bin], 1);
      stW[r] = (sv[k] << 8) | (dv[k] & 255);
      stB[r] = (unsigned short)bin;
    }
  }
  __syncthreads();
  int tot = psum[511];
  for (int idx = t; idx < tot; idx += 1024)
    edges1[gofs[stB[idx]] + idx] = (unsigned)stW[idx];  // 64B bucket runs
  __syncthreads();
  // ======== split 2: by src bucket (byte payload) ========
  if (t < 512) hist[t] = 0;
  __syncthreads();
  #pragma unroll
  for (int k = 0; k < 8; k++)
    if (dv[k] >= 0) atomicAdd(&hist[sv[k] >> 8], 1);
  __syncthreads();
  if (t < 512) psum[t] = hist[t];
  __syncthreads();
  for (int off = 1; off < 512; off <<= 1) {
    int a = 0;
    if (t < 512 && t >= off) a = psum[t - off];
    __syncthreads();
    if (t < 512) psum[t] += a;
    __syncthreads();
  }
  if (t < 512) {
    int cnt = hist[t];
    int base = psum[t] - cnt;
    curL[t] = base;
    int g = cnt ? atomicAdd(&cur_s[t * CPAD], cnt) : 0;
    gofs[t] = g - base;
  }
  __syncthreads();
  #pragma unroll
  for (int k = 0; k < 8; k++) {
    if (dv[k] >= 0) {
      int bin = sv[k] >> 8;
      int r = atomicAdd(&curL[bin], 1);
      stW[r] = sv[k] & 255;
      stB[r] = (unsigned short)bin;
    }
  }
  __syncthreads();
  for (int idx = t; idx < tot; idx += 1024)
    srcbuf[gofs[stB[idx]] + idx] = (unsigned char)stW[idx];
}

// ---------------- per-bucket fine sort + degrees + fused bf16 cast (v2) ----------
// block b owns nodes [b*256, +256); 1024 threads, full bucket staged in LDS.
__global__ __launch_bounds__(1024) void sort_place(
    const unsigned* __restrict__ edges1, const unsigned char* __restrict__ srcbuf,
    const int* __restrict__ cur_d, const int* __restrict__ cur_s,
    const float* __restrict__ node_feat,
    int2* __restrict__ row_be, float* __restrict__ inv_in, float* __restrict__ inv_out,
    unsigned short* __restrict__ xb, int* __restrict__ col, int n) {
  __shared__ int sEdge[CAPB];         // 32 KB staged bucket edges
  __shared__ int sOut[CAPB];          // 32 KB sorted src ids (full size, no fallback)
  __shared__ int hist[256], cur[256], psum[256], dhist[256];
  __shared__ float sInvO[256];
  int b = blockIdx.x, t = threadIdx.x;
  int sbase = b * CAPB;
  int m = min(cur_d[b * CPAD] - sbase, CAPB);   // bucket edge count
  int ms = min(cur_s[b * CPAD] - sbase, CAPB);  // src-side byte count
  int rstart = b << 8;
  int nrows = min(256, n - rstart);
  if (t < 256) { hist[t] = 0; dhist[t] = 0; }
  __syncthreads();
  // one global pass: stage edges; out-degree hist straight from byte buffer
  for (int k = t; k < m; k += 1024) sEdge[k] = (int)edges1[sbase + k];
  for (int k = t; k < ms; k += 1024) atomicAdd(&dhist[srcbuf[sbase + k]], 1);
  __syncthreads();
  // in-degree hist from LDS
  for (int k = t; k < m; k += 1024) atomicAdd(&hist[sEdge[k] & 255], 1);
  __syncthreads();
  int h0 = 0;
  if (t < 256) { h0 = hist[t]; psum[t] = h0; }
  __syncthreads();
  for (int off = 1; off < 256; off <<= 1) {
    int a = 0;
    if (t < 256 && t >= off) a = psum[t - off];
    __syncthreads();
    if (t < 256) psum[t] += a;
    __syncthreads();
  }
  if (t < 256) {
    int ex = psum[t] - h0;
    float ivo = rsqrtf(fmaxf((float)dhist[t], 1.0f));
    sInvO[t] = ivo;
    if (t < nrows) {
      row_be[rstart + t] = make_int2(sbase + ex, sbase + ex + h0);
      inv_in[rstart + t] = rsqrtf(fmaxf((float)h0, 1.0f));
      inv_out[rstart + t] = ivo;
    }
    cur[t] = ex;
  }
  __syncthreads();
  // place LDS -> LDS (pos < m <= CAPB always)
  for (int k = t; k < m; k += 1024) {
    int v = sEdge[k];
    int pos = atomicAdd(&cur[v & 255], 1);
    sOut[pos] = v >> 8;
  }
  __syncthreads();
  for (int k = t; k < m; k += 1024) col[sbase + k] = sOut[k];
  // fused pre-scaled bf16 cast of this block's feature rows
  int total4 = nrows * 16;            // 16 float4 per row
  const float4* nf4 = (const float4*)(node_feat + (size_t)rstart * 64);
  unsigned short* xrow = xb + (size_t)rstart * 64;
  for (int u = t; u < total4; u += 1024) {
    float iv = sInvO[u >> 4];
    float4 v = nf4[u];
    ushort4 o;
    o.x = f2bf(v.x * iv); o.y = f2bf(v.y * iv);
    o.z = f2bf(v.z * iv); o.w = f2bf(v.w * iv);
    *(ushort4*)&xrow[(size_t)u * 4] = o;
  }
}

// ---------------- fused SpMM + GEMM + bias + ReLU + pool + next-layer bf16 cast ----------------
// 512 threads own 64 rows. Phase 1: 8 waves x 8 rows, wave-per-row gather (16 edges
// in flight, degree-adaptive), shfl-reduce, scaled store into transposed LDS tile sXT.
// Phase 2: 64x64 @ 64x64 GEMM (W from global, L1-resident). NT stores ONLY on
// out_cat/out_pool (never re-read). sXT pad 66: write-side conflict 8-way -> 4-way.
__global__ __launch_bounds__(512) void spmm_gemm(
    const unsigned short* __restrict__ xb,
    const int2* __restrict__ row_be,
    const int* __restrict__ col,
    const float* __restrict__ inv_in, const float* __restrict__ inv_out,
    const float* __restrict__ W, const float* __restrict__ bias,
    float* __restrict__ out_cat, float* __restrict__ out_pool,
    unsigned short* __restrict__ xb_next, int n) {
  __shared__ float sXT[64][66];       // [feat][row], pad 66 (264B stride: 4-way, 8B-aligned)
  int t = threadIdx.x;
  int row0 = blockIdx.x << 6;         // 64 rows per block
  int lane = t & 63;
  int g = lane >> 3;            // edge group 0..7
  int l8 = (lane & 7) << 3;     // feature offset (8 feats = 16 B)
  int wv = t >> 6;              // wave 0..7, each owns 8 rows
  for (int k = 0; k < 8; k++) {
    int rl = wv * 8 + k;
    int row = row0 + rl;
    float v = 0.f;
    if (row < n) {              // wave-uniform branch
      int2 be = row_be[row];    // one 8B load: [beg, end)
      int s = be.x, e = be.y;
      float inv = inv_in[row];  // hoisted: overlaps with the edge loop below
      float a0 = 0, a1 = 0, a2 = 0, a3 = 0, a4 = 0, a5 = 0, a6 = 0, a7 = 0;
      int ec = e - 1;
      for (int i = s + g; i < e; i += 16) {   // 16 edges in flight, deg-adaptive
        int i1 = i + 8;
        int c0 = col[i];
        int c1 = col[min(i1, ec)];
        float m1 = (i1 < e) ? 1.f : 0.f;
        uint4 r0 = *(const uint4*)&xb[(size_t)c0 * 64 + l8];
        uint4 r1 = *(const uint4*)&xb[(size_t)c1 * 64 + l8];
        a0 += bflo(r0.x); a1 += bfhi(r0.x); a2 += bflo(r0.y); a3 += bfhi(r0.y);
        a4 += bflo(r0.z); a5 += bfhi(r0.z); a6 += bflo(r0.w); a7 += bfhi(r0.w);
        a0 = fmaf(m1, bflo(r1.x), a0); a1 = fmaf(m1, bfhi(r1.x), a1);
        a2 = fmaf(m1, bflo(r1.y), a2); a3 = fmaf(m1, bfhi(r1.y), a3);
        a4 = fmaf(m1, bflo(r1.z), a4); a5 = fmaf(m1, bfhi(r1.z), a5);
        a6 = fmaf(m1, bflo(r1.w), a6); a7 = fmaf(m1, bfhi(r1.w), a7);
      }
      // butterfly over edge groups (bits 3..5 of lane): all lanes end with full sums
      a0 += __shfl_xor(a0, 8); a0 += __shfl_xor(a0, 16); a0 += __shfl_xor(a0, 32);
      a1 += __shfl_xor(a1, 8); a1 += __shfl_xor(a1, 16); a1 += __shfl_xor(a1, 32);
      a2 += __shfl_xor(a2, 8); a2 += __shfl_xor(a2, 16); a2 += __shfl_xor(a2, 32);
      a3 += __shfl_xor(a3, 8); a3 += __shfl_xor(a3, 16); a3 += __shfl_xor(a3, 32);
      a4 += __shfl_xor(a4, 8); a4 += __shfl_xor(a4, 16); a4 += __shfl_xor(a4, 32);
      a5 += __shfl_xor(a5, 8); a5 += __shfl_xor(a5, 16); a5 += __shfl_xor(a5, 32);
      a6 += __shfl_xor(a6, 8); a6 += __shfl_xor(a6, 16); a6 += __shfl_xor(a6, 32);
      a7 += __shfl_xor(a7, 8); a7 += __shfl_xor(a7, 16); a7 += __shfl_xor(a7, 32);
      // lane (g,l8) contributes feature f = l8 + g (cndmask tree, no scratch array)
      float s0 = (g & 1) ? a1 : a0;
      float s1 = (g & 1) ? a3 : a2;
      float s2 = (g & 1) ? a5 : a4;
      float s3 = (g & 1) ? a7 : a6;
      float u0 = (g & 2) ? s1 : s0;
      float u1 = (g & 2) ? s3 : s2;
      v = ((g & 4) ? u1 : u0) * inv;
    }
    sXT[l8 + g][rl] = v;        // 64 lanes -> 64 feats of column rl (4-way, single store)
  }
  __syncthreads();
  // ---- GEMM phase: 512 threads, 2x4 micro-tile each -> 64 rows x 64 cols ----
  int tj = t & 15, tr = t >> 4;       // tj: col group 0..15, tr: row group 0..31
  int j4 = tj << 2, r2 = tr << 1;
  const float4 bv = *(const float4*)&bias[j4];
  float4 a0 = bv, a1 = bv;
  #pragma unroll 8
  for (int f = 0; f < 64; f++) {
    float4 w  = *(const float4*)&W[f * 64 + j4];   // L1-resident after first block
    float2 xv = *(const float2*)&sXT[f][r2];
    a0.x = fmaf(xv.x, w.x, a0.x); a0.y = fmaf(xv.x, w.y, a0.y);
    a0.z = fmaf(xv.x, w.z, a0.z); a0.w = fmaf(xv.x, w.w, a0.w);
    a1.x = fmaf(xv.y, w.x, a1.x); a1.y = fmaf(xv.y, w.y, a1.y);
    a1.z = fmaf(xv.y, w.z, a1.z); a1.w = fmaf(xv.y, w.w, a1.w);
  }
  float4 accs[2] = {a0, a1};
  #pragma unroll
  for (int ri = 0; ri < 2; ri++) {
    int row = row0 + r2 + ri;
    if (row < n) {
      float4 h = accs[ri];
      h.x = fmaxf(h.x, 0.f); h.y = fmaxf(h.y, 0.f);
      h.z = fmaxf(h.z, 0.f); h.w = fmaxf(h.w, 0.f);
      nt_store_f4(h, &out_cat[(size_t)row * 192 + j4]);
      if (xb_next) {
        float sc = inv_out[row];
        ushort4 o;
        o.x = f2bf(h.x * sc); o.y = f2bf(h.y * sc);
        o.z = f2bf(h.z * sc); o.w = f2bf(h.w * sc);
        *(ushort4*)&xb_next[(size_t)row * 64 + j4] = o;
      }
      float part = h.x + h.y + h.z + h.w;
      part += __shfl_xor(part, 1);
      part += __shfl_xor(part, 2);
      part += __shfl_xor(part, 4);
      part += __shfl_xor(part, 8);
      if (tj == 0) __builtin_nontemporal_store(part, &out_pool[row]);
    }
  }
}

// ---------------- launch ----------------

extern "C" void kernel_launch(void* const* d_in, const int* in_sizes, int n_in,
                              void* d_out, int out_size, void* d_ws, size_t ws_size,
                              hipStream_t stream) {
  const float* node_feat = (const float*)d_in[0];
  const int* src = (const int*)d_in[1];
  const int* dst = (const int*)d_in[2];
  const float* Ws[3] = {(const float*)d_in[4], (const float*)d_in[6], (const float*)d_in[8]};
  const float* bs[3] = {(const float*)d_in[5], (const float*)d_in[7], (const float*)d_in[9]};
  float* out = (float*)d_out;
  int n = in_sizes[0] / 64;
  int e = in_sizes[1];
  int nbb = (n + 255) >> 8;         // buckets of 256 rows (391 for n=100k)
  int nblk = (e + EPB - 1) / EPB;   // edge blocks (196)
  size_t slots = (size_t)nbb * CAPB;

  char* p = (char*)d_ws;
  unsigned short* xba = (unsigned short*)p; p += (size_t)n * 64 * sizeof(unsigned short);
  unsigned short* xbb = (unsigned short*)p; p += (size_t)n * 64 * sizeof(unsigned short);
  float* inv_out = (float*)p;   p += (size_t)n * sizeof(float);
  float* inv_in = (float*)p;    p += (size_t)n * sizeof(float);
  int2* row_be = (int2*)p;      p += (size_t)n * sizeof(int2);
  int* cur_d = (int*)p;         p += 512 * CPAD * sizeof(int);
  int* cur_s = (int*)p;         p += 512 * CPAD * sizeof(int);
  unsigned* edges1 = (unsigned*)p; p += slots * sizeof(unsigned);
  int* col = (int*)p;           p += slots * sizeof(int);
  unsigned char* srcbuf = (unsigned char*)p; p += slots;

  init_zero<<<32, 256, 0, stream>>>(cur_d, cur_s);
  scatter_both<<<nblk, 1024, 0, stream>>>(src, dst, e, cur_d, cur_s, edges1, srcbuf);
  sort_place<<<nbb, 1024, 0, stream>>>(edges1, srcbuf, cur_d, cur_s, node_feat,
                                       row_be, inv_in, inv_out, xba, col, n);

  float* cat_base = out + (size_t)3 * n;
  int nfb = (n + 63) >> 6;          // fused blocks: 64 rows each (1563 for n=100k)
  // xb double-buffered: fused kernel reads features while writing next layer's.
  spmm_gemm<<<nfb, 512, 0, stream>>>(xba, row_be, col, inv_in, inv_out,
      Ws[0], bs[0], cat_base + 0 * 64, out + (size_t)0 * n, xbb, n);
  spmm_gemm<<<nfb, 512, 0, stream>>>(xbb, row_be, col, inv_in, inv_out,
      Ws[1], bs[1], cat_base + 1 * 64, out + (size_t)1 * n, xba, n);
  spmm_gemm<<<nfb, 512, 0, stream>>>(xba, row_be, col, inv_in, inv_out,
      Ws[2], bs[2], cat_base + 2 * 64, out + (size_t)2 * n, (unsigned short*)nullptr, n);
}

// Round 14
// 332.391 us; speedup vs baseline: 1.6622x; 1.0038x over previous
//
#include <hip/hip_runtime.h>

// GCN: n=100k nodes, E=1.6M edges, D=64, 3 layers.
// Round 22: barrier-diet. R21 = 333.6 best. spmm floor confirmed by arithmetic:
// FETCH 79MB == compulsory (86k unique 128B rows/XCD x 8), MSHR-bound at ~260
// outstanding misses/XCD; data is uniform-random -> no locality exists. Remaining
// code-level waste: Hillis-Steele scans cost ~18 barriers each (2x in scatter at
// <1 block/CU = pure serial time, 1x in sort). Replaced with wave shfl_up scans
// (2 barriers each). Everything else byte-identical to R21.
// Packing (src<<8)|(dst&255) needs n <= 2^17, nbb <= 512.

#define CAPB 8192      // per-bucket slot capacity, dst words & src bytes (mean 4096, 64 sigma)
#define EPB  8192      // edges per scatter block
#define CPAD 16        // cursor stride in ints: one counter per 64B cache line

typedef float f4v __attribute__((ext_vector_type(4)));

__device__ __forceinline__ unsigned short f2bf(float f) {   // RNE fp32->bf16
  unsigned u = __float_as_uint(f);
  u += 0x7fff + ((u >> 16) & 1);
  return (unsigned short)(u >> 16);
}
__device__ __forceinline__ float bflo(unsigned u) { return __uint_as_float(u << 16); }
__device__ __forceinline__ float bfhi(unsigned u) { return __uint_as_float(u & 0xffff0000u); }

__device__ __forceinline__ void nt_store_f4(float4 v, float* p) {
  f4v x = {v.x, v.y, v.z, v.w};
  __builtin_nontemporal_store(x, (f4v*)p);
}

// wave-local inclusive scan (64 lanes)
__device__ __forceinline__ int wave_iscan(int v, int ln) {
  #pragma unroll
  for (int off = 1; off < 64; off <<= 1) {
    int u = __shfl_up(v, off);
    if (ln >= off) v += u;
  }
  return v;
}

// ---------------- init: padded cursors cur_d/cur_s [b*CPAD] = b*CAPB ----------------
__global__ void init_zero(int* __restrict__ cur_d, int* __restrict__ cur_s) {
  int idx = blockIdx.x * 256 + threadIdx.x;
  if (idx < 512 * CPAD) {
    int v = (idx % CPAD == 0) ? (idx / CPAD) * CAPB : 0;
    cur_d[idx] = v;
    cur_s[idx] = v;
  }
}

// ---------------- one read pass, two LDS-staged coalesced splits ----------------
// 1024 threads x 8 edges = 8192 edges/block (196 blocks): 64B bucket runs.
// Scans: wave shfl (2 barriers) instead of Hillis-Steele (18).
__global__ __launch_bounds__(1024) void scatter_both(
    const int* __restrict__ src, const int* __restrict__ dst, int e,
    int* __restrict__ cur_d, int* __restrict__ cur_s,
    unsigned* __restrict__ edges1, unsigned char* __restrict__ srcbuf) {
  __shared__ int stW[EPB];            // 32 KB payloads in bucket order
  __shared__ unsigned short stB[EPB]; // 16 KB bin of each placed element
  __shared__ int hist[512], curL[512], gofs[512];
  __shared__ int wtot[8];
  __shared__ int totS;
  int t = threadIdx.x, b = blockIdx.x;
  int wv = t >> 6, ln = t & 63;
  int i0 = b * EPB + 8 * t;
  int sv[8], dv[8];
  #pragma unroll
  for (int k = 0; k < 8; k += 4) {
    int i = i0 + k;
    if (i + 3 < e) {
      int4 s4 = *(const int4*)&src[i];
      int4 d4 = *(const int4*)&dst[i];
      sv[k] = s4.x; sv[k+1] = s4.y; sv[k+2] = s4.z; sv[k+3] = s4.w;
      dv[k] = d4.x; dv[k+1] = d4.y; dv[k+2] = d4.z; dv[k+3] = d4.w;
    } else {
      #pragma unroll
      for (int j = 0; j < 4; j++) {
        int idx = i + j;
        if (idx < e) { sv[k+j] = src[idx]; dv[k+j] = dst[idx]; }
        else { sv[k+j] = -1; dv[k+j] = -1; }
      }
    }
  }
  // ======== split 1: by dst bucket ========
  if (t < 512) hist[t] = 0;
  __syncthreads();
  #pragma unroll
  for (int k = 0; k < 8; k++)
    if (dv[k] >= 0) atomicAdd(&hist[dv[k] >> 8], 1);
  __syncthreads();
  // inclusive scan of hist[0..511]: waves 0-7 scan 64 bins each
  {
    int v = (t < 512) ? hist[t] : 0;
    v = wave_iscan(v, ln);
    if (t < 512 && ln == 63) wtot[wv] = v;
    __syncthreads();
    if (t == 0) {
      int acc = 0;
      #pragma unroll
      for (int w = 0; w < 8; w++) { int c = wtot[w]; wtot[w] = acc; acc += c; }
      totS = acc;
    }
    __syncthreads();
    if (t < 512) {
      int incl = v + wtot[wv];
      int cnt = hist[t];
      int base = incl - cnt;
      curL[t] = base;
      int g = cnt ? atomicAdd(&cur_d[t * CPAD], cnt) : 0;
      gofs[t] = g - base;
    }
  }
  __syncthreads();
  #pragma unroll
  for (int k = 0; k < 8; k++) {
    if (dv[k] >= 0) {
      int bin = dv[k] >> 8;
      int r = atomicAdd(&curL[bin], 1);
      stW[r] = (sv[k] << 8) | (dv[k] & 255);
      stB[r] = (unsigned short)bin;
    }
  }
  __syncthreads();
  int tot = totS;
  for (int idx = t; idx < tot; idx += 1024)
    edges1[gofs[stB[idx]] + idx] = (unsigned)stW[idx];  // 64B bucket runs
  __syncthreads();
  // ======== split 2: by src bucket (byte payload) ========
  if (t < 512) hist[t] = 0;
  __syncthreads();
  #pragma unroll
  for (int k = 0; k < 8; k++)
    if (dv[k] >= 0) atomicAdd(&hist[sv[k] >> 8], 1);
  __syncthreads();
  {
    int v = (t < 512) ? hist[t] : 0;
    v = wave_iscan(v, ln);
    if (t < 512 && ln == 63) wtot[wv] = v;
    __syncthreads();
    if (t == 0) {
      int acc = 0;
      #pragma unroll
      for (int w = 0; w < 8; w++) { int c = wtot[w]; wtot[w] = acc; acc += c; }
    }
    __syncthreads();
    if (t < 512) {
      int incl = v + wtot[wv];
      int cnt = hist[t];
      int base = incl - cnt;
      curL[t] = base;
      int g = cnt ? atomicAdd(&cur_s[t * CPAD], cnt) : 0;
      gofs[t] = g - base;
    }
  }
  __syncthreads();
  #pragma unroll
  for (int k = 0; k < 8; k++) {
    if (dv[k] >= 0) {
      int bin = sv[k] >> 8;
      int r = atomicAdd(&curL[bin], 1);
      stW[r] = sv[k] & 255;
      stB[r] = (unsigned short)bin;
    }
  }
  __syncthreads();
  for (int idx = t; idx < tot; idx += 1024)
    srcbuf[gofs[stB[idx]] + idx] = (unsigned char)stW[idx];
}

// ---------------- per-bucket fine sort + degrees + fused bf16 cast ----------
// block b owns nodes [b*256, +256); 1024 threads, full bucket staged in LDS.
// 256-bin scan via wave shfl (2 barriers).
__global__ __launch_bounds__(1024) void sort_place(
    const unsigned* __restrict__ edges1, const unsigned char* __restrict__ srcbuf,
    const int* __restrict__ cur_d, const int* __restrict__ cur_s,
    const float* __restrict__ node_feat,
    int2* __restrict__ row_be, float* __restrict__ inv_in, float* __restrict__ inv_out,
    unsigned short* __restrict__ xb, int* __restrict__ col, int n) {
  __shared__ int sEdge[CAPB];         // 32 KB staged bucket edges
  __shared__ int sOut[CAPB];          // 32 KB sorted src ids
  __shared__ int hist[256], cur[256], dhist[256];
  __shared__ float sInvO[256];
  __shared__ int wtot[4];
  int b = blockIdx.x, t = threadIdx.x;
  int wv = t >> 6, ln = t & 63;
  int sbase = b * CAPB;
  int m = min(cur_d[b * CPAD] - sbase, CAPB);   // bucket edge count
  int ms = min(cur_s[b * CPAD] - sbase, CAPB);  // src-side byte count
  int rstart = b << 8;
  int nrows = min(256, n - rstart);
  if (t < 256) { hist[t] = 0; dhist[t] = 0; }
  __syncthreads();
  // one global pass: stage edges; out-degree hist straight from byte buffer
  for (int k = t; k < m; k += 1024) sEdge[k] = (int)edges1[sbase + k];
  for (int k = t; k < ms; k += 1024) atomicAdd(&dhist[srcbuf[sbase + k]], 1);
  __syncthreads();
  // in-degree hist from LDS
  for (int k = t; k < m; k += 1024) atomicAdd(&hist[sEdge[k] & 255], 1);
  __syncthreads();
  // inclusive scan of hist[0..255]: waves 0-3
  {
    int v = (t < 256) ? hist[t] : 0;
    v = wave_iscan(v, ln);
    if (t < 256 && ln == 63) wtot[wv] = v;
    __syncthreads();
    if (t == 0) {
      int acc = 0;
      #pragma unroll
      for (int w = 0; w < 4; w++) { int c = wtot[w]; wtot[w] = acc; acc += c; }
    }
    __syncthreads();
    if (t < 256) {
      int h0 = hist[t];
      int incl = v + wtot[wv];
      int ex = incl - h0;
      float ivo = rsqrtf(fmaxf((float)dhist[t], 1.0f));
      sInvO[t] = ivo;
      if (t < nrows) {
        row_be[rstart + t] = make_int2(sbase + ex, sbase + ex + h0);
        inv_in[rstart + t] = rsqrtf(fmaxf((float)h0, 1.0f));
        inv_out[rstart + t] = ivo;
      }
      cur[t] = ex;
    }
  }
  __syncthreads();
  // place LDS -> LDS (pos < m <= CAPB always)
  for (int k = t; k < m; k += 1024) {
    int v = sEdge[k];
    int pos = atomicAdd(&cur[v & 255], 1);
    sOut[pos] = v >> 8;
  }
  __syncthreads();
  for (int k = t; k < m; k += 1024) col[sbase + k] = sOut[k];
  // fused pre-scaled bf16 cast of this block's feature rows
  int total4 = nrows * 16;            // 16 float4 per row
  const float4* nf4 = (const float4*)(node_feat + (size_t)rstart * 64);
  unsigned short* xrow = xb + (size_t)rstart * 64;
  for (int u = t; u < total4; u += 1024) {
    float iv = sInvO[u >> 4];
    float4 v = nf4[u];
    ushort4 o;
    o.x = f2bf(v.x * iv); o.y = f2bf(v.y * iv);
    o.z = f2bf(v.z * iv); o.w = f2bf(v.w * iv);
    *(ushort4*)&xrow[(size_t)u * 4] = o;
  }
}

// ---------------- fused SpMM + GEMM + bias + ReLU + pool + next-layer bf16 cast ----------------
// 512 threads own 64 rows. Phase 1: 8 waves x 8 rows, wave-per-row gather (16 edges
// in flight, degree-adaptive), shfl-reduce, scaled store into transposed LDS tile sXT.
// Phase 2: 64x64 @ 64x64 GEMM (W from global, L1-resident). NT stores ONLY on
// out_cat/out_pool (never re-read). sXT pad 66 (4-way, 8B-aligned).
__global__ __launch_bounds__(512) void spmm_gemm(
    const unsigned short* __restrict__ xb,
    const int2* __restrict__ row_be,
    const int* __restrict__ col,
    const float* __restrict__ inv_in, const float* __restrict__ inv_out,
    const float* __restrict__ W, const float* __restrict__ bias,
    float* __restrict__ out_cat, float* __restrict__ out_pool,
    unsigned short* __restrict__ xb_next, int n) {
  __shared__ float sXT[64][66];       // [feat][row], pad 66 (264B stride)
  int t = threadIdx.x;
  int row0 = blockIdx.x << 6;         // 64 rows per block
  int lane = t & 63;
  int g = lane >> 3;            // edge group 0..7
  int l8 = (lane & 7) << 3;     // feature offset (8 feats = 16 B)
  int wv = t >> 6;              // wave 0..7, each owns 8 rows
  for (int k = 0; k < 8; k++) {
    int rl = wv * 8 + k;
    int row = row0 + rl;
    float v = 0.f;
    if (row < n) {              // wave-uniform branch
      int2 be = row_be[row];    // one 8B load: [beg, end)
      int s = be.x, e = be.y;
      float inv = inv_in[row];  // hoisted: overlaps with the edge loop below
      float a0 = 0, a1 = 0, a2 = 0, a3 = 0, a4 = 0, a5 = 0, a6 = 0, a7 = 0;
      int ec = e - 1;
      for (int i = s + g; i < e; i += 16) {   // 16 edges in flight, deg-adaptive
        int i1 = i + 8;
        int c0 = col[i];
        int c1 = col[min(i1, ec)];
        float m1 = (i1 < e) ? 1.f : 0.f;
        uint4 r0 = *(const uint4*)&xb[(size_t)c0 * 64 + l8];
        uint4 r1 = *(const uint4*)&xb[(size_t)c1 * 64 + l8];
        a0 += bflo(r0.x); a1 += bfhi(r0.x); a2 += bflo(r0.y); a3 += bfhi(r0.y);
        a4 += bflo(r0.z); a5 += bfhi(r0.z); a6 += bflo(r0.w); a7 += bfhi(r0.w);
        a0 = fmaf(m1, bflo(r1.x), a0); a1 = fmaf(m1, bfhi(r1.x), a1);
        a2 = fmaf(m1, bflo(r1.y), a2); a3 = fmaf(m1, bfhi(r1.y), a3);
        a4 = fmaf(m1, bflo(r1.z), a4); a5 = fmaf(m1, bfhi(r1.z), a5);
        a6 = fmaf(m1, bflo(r1.w), a6); a7 = fmaf(m1, bfhi(r1.w), a7);
      }
      // butterfly over edge groups (bits 3..5 of lane): all lanes end with full sums
      a0 += __shfl_xor(a0, 8); a0 += __shfl_xor(a0, 16); a0 += __shfl_xor(a0, 32);
      a1 += __shfl_xor(a1, 8); a1 += __shfl_xor(a1, 16); a1 += __shfl_xor(a1, 32);
      a2 += __shfl_xor(a2, 8); a2 += __shfl_xor(a2, 16); a2 += __shfl_xor(a2, 32);
      a3 += __shfl_xor(a3, 8); a3 += __shfl_xor(a3, 16); a3 += __shfl_xor(a3, 32);
      a4 += __shfl_xor(a4, 8); a4 += __shfl_xor(a4, 16); a4 += __shfl_xor(a4, 32);
      a5 += __shfl_xor(a5, 8); a5 += __shfl_xor(a5, 16); a5 += __shfl_xor(a5, 32);
      a6 += __shfl_xor(a6, 8); a6 += __shfl_xor(a6, 16); a6 += __shfl_xor(a6, 32);
      a7 += __shfl_xor(a7, 8); a7 += __shfl_xor(a7, 16); a7 += __shfl_xor(a7, 32);
      // lane (g,l8) contributes feature f = l8 + g (cndmask tree, no scratch array)
      float s0 = (g & 1) ? a1 : a0;
      float s1 = (g & 1) ? a3 : a2;
      float s2 = (g & 1) ? a5 : a4;
      float s3 = (g & 1) ? a7 : a6;
      float u0 = (g & 2) ? s1 : s0;
      float u1 = (g & 2) ? s3 : s2;
      v = ((g & 4) ? u1 : u0) * inv;
    }
    sXT[l8 + g][rl] = v;        // 64 lanes -> 64 feats of column rl (4-way, single store)
  }
  __syncthreads();
  // ---- GEMM phase: 512 threads, 2x4 micro-tile each -> 64 rows x 64 cols ----
  int tj = t & 15, tr = t >> 4;       // tj: col group 0..15, tr: row group 0..31
  int j4 = tj << 2, r2 = tr << 1;
  const float4 bv = *(const float4*)&bias[j4];
  float4 a0 = bv, a1 = bv;
  #pragma unroll 8
  for (int f = 0; f < 64; f++) {
    float4 w  = *(const float4*)&W[f * 64 + j4];   // L1-resident after first block
    float2 xv = *(const float2*)&sXT[f][r2];
    a0.x = fmaf(xv.x, w.x, a0.x); a0.y = fmaf(xv.x, w.y, a0.y);
    a0.z = fmaf(xv.x, w.z, a0.z); a0.w = fmaf(xv.x, w.w, a0.w);
    a1.x = fmaf(xv.y, w.x, a1.x); a1.y = fmaf(xv.y, w.y, a1.y);
    a1.z = fmaf(xv.y, w.z, a1.z); a1.w = fmaf(xv.y, w.w, a1.w);
  }
  float4 accs[2] = {a0, a1};
  #pragma unroll
  for (int ri = 0; ri < 2; ri++) {
    int row = row0 + r2 + ri;
    if (row < n) {
      float4 h = accs[ri];
      h.x = fmaxf(h.x, 0.f); h.y = fmaxf(h.y, 0.f);
      h.z = fmaxf(h.z, 0.f); h.w = fmaxf(h.w, 0.f);
      nt_store_f4(h, &out_cat[(size_t)row * 192 + j4]);
      if (xb_next) {
        float sc = inv_out[row];
        ushort4 o;
        o.x = f2bf(h.x * sc); o.y = f2bf(h.y * sc);
        o.z = f2bf(h.z * sc); o.w = f2bf(h.w * sc);
        *(ushort4*)&xb_next[(size_t)row * 64 + j4] = o;
      }
      float part = h.x + h.y + h.z + h.w;
      part += __shfl_xor(part, 1);
      part += __shfl_xor(part, 2);
      part += __shfl_xor(part, 4);
      part += __shfl_xor(part, 8);
      if (tj == 0) __builtin_nontemporal_store(part, &out_pool[row]);
    }
  }
}

// ---------------- launch ----------------

extern "C" void kernel_launch(void* const* d_in, const int* in_sizes, int n_in,
                              void* d_out, int out_size, void* d_ws, size_t ws_size,
                              hipStream_t stream) {
  const float* node_feat = (const float*)d_in[0];
  const int* src = (const int*)d_in[1];
  const int* dst = (const int*)d_in[2];
  const float* Ws[3] = {(const float*)d_in[4], (const float*)d_in[6], (const float*)d_in[8]};
  const float* bs[3] = {(const float*)d_in[5], (const float*)d_in[7], (const float*)d_in[9]};
  float* out = (float*)d_out;
  int n = in_sizes[0] / 64;
  int e = in_sizes[1];
  int nbb = (n + 255) >> 8;         // buckets of 256 rows (391 for n=100k)
  int nblk = (e + EPB - 1) / EPB;   // edge blocks (196)
  size_t slots = (size_t)nbb * CAPB;

  char* p = (char*)d_ws;
  unsigned short* xba = (unsigned short*)p; p += (size_t)n * 64 * sizeof(unsigned short);
  unsigned short* xbb = (unsigned short*)p; p += (size_t)n * 64 * sizeof(unsigned short);
  float* inv_out = (float*)p;   p += (size_t)n * sizeof(float);
  float* inv_in = (float*)p;    p += (size_t)n * sizeof(float);
  int2* row_be = (int2*)p;      p += (size_t)n * sizeof(int2);
  int* cur_d = (int*)p;         p += 512 * CPAD * sizeof(int);
  int* cur_s = (int*)p;         p += 512 * CPAD * sizeof(int);
  unsigned* edges1 = (unsigned*)p; p += slots * sizeof(unsigned);
  int* col = (int*)p;           p += slots * sizeof(int);
  unsigned char* srcbuf = (unsigned char*)p; p += slots;

  init_zero<<<32, 256, 0, stream>>>(cur_d, cur_s);
  scatter_both<<<nblk, 1024, 0, stream>>>(src, dst, e, cur_d, cur_s, edges1, srcbuf);
  sort_place<<<nbb, 1024, 0, stream>>>(edges1, srcbuf, cur_d, cur_s, node_feat,
                                       row_be, inv_in, inv_out, xba, col, n);

  float* cat_base = out + (size_t)3 * n;
  int nfb = (n + 63) >> 6;          // fused blocks: 64 rows each (1563 for n=100k)
  // xb double-buffered: fused kernel reads features while writing next layer's.
  spmm_gemm<<<nfb, 512, 0, stream>>>(xba, row_be, col, inv_in, inv_out,
      Ws[0], bs[0], cat_base + 0 * 64, out + (size_t)0 * n, xbb, n);
  spmm_gemm<<<nfb, 512, 0, stream>>>(xbb, row_be, col, inv_in, inv_out,
      Ws[1], bs[1], cat_base + 1 * 64, out + (size_t)1 * n, xba, n);
  spmm_gemm<<<nfb, 512, 0, stream>>>(xba, row_be, col, inv_in, inv_out,
      Ws[2], bs[2], cat_base + 2 * 64, out + (size_t)2 * n, (unsigned short*)nullptr, n);
}